// Round 1
// baseline (2710.104 us; speedup 1.0000x reference)
//
#include <hip/hip_runtime.h>

static constexpr int NX = 128, NY = 128, NZ = 128;
static constexpr int NPTS = 100000;
static constexpr int NCH = 8;
static constexpr int MESH = NX * NY * NZ;  // 2097152 nodes

// P3M order-4 per-axis weights, x in [-1/2, 1/2]
__device__ __forceinline__ void axis_weights(float x, float w[4]) {
    float x2 = x * x, x3 = x2 * x;
    const float c = 1.0f / 48.0f;
    w[0] = c * (1.0f  - 6.0f  * x + 12.0f * x2 - 8.0f  * x3);
    w[1] = c * (23.0f - 30.0f * x - 12.0f * x2 + 24.0f * x3);
    w[2] = c * (23.0f + 30.0f * x - 12.0f * x2 - 24.0f * x3);
    w[3] = c * (1.0f  + 6.0f  * x + 12.0f * x2 + 8.0f  * x3);
}

// Computes base mesh index (floor) and per-axis weights for particle p.
__device__ __forceinline__ void setup_particle(const float* __restrict__ pos,
                                               const float* __restrict__ cell,
                                               int p,
                                               int& ix, int& iy, int& iz,
                                               float wx[4], float wy[4], float wz[4]) {
    // inverse of row-major 3x3 cell via adjugate; pos_rel[j] = 128 * sum_k pos[k]*inv[k][j]
    // inv[k][j] = Cof[j][k]/det
    float a = cell[0], b = cell[1], c = cell[2];
    float d = cell[3], e = cell[4], f = cell[5];
    float g = cell[6], h = cell[7], i9 = cell[8];
    float c00 = e * i9 - f * h, c01 = f * g - d * i9, c02 = d * h - e * g;
    float c10 = c * h - b * i9, c11 = a * i9 - c * g, c12 = b * g - a * h;
    float c20 = b * f - c * e,  c21 = c * d - a * f,  c22 = a * e - b * d;
    float det = a * c00 + b * c01 + c * c02;
    float s = 128.0f / det;
    float p0 = pos[p * 3 + 0], p1 = pos[p * 3 + 1], p2 = pos[p * 3 + 2];
    float rx = s * (p0 * c00 + p1 * c01 + p2 * c02);
    float ry = s * (p0 * c10 + p1 * c11 + p2 * c12);
    float rz = s * (p0 * c20 + p1 * c21 + p2 * c22);
    float fx = floorf(rx), fy = floorf(ry), fz = floorf(rz);
    ix = (int)fx; iy = (int)fy; iz = (int)fz;
    axis_weights(rx - fx - 0.5f, wx);
    axis_weights(ry - fy - 0.5f, wy);
    axis_weights(rz - fz - 0.5f, wz);
}

// 4 threads per particle; thread handles one x-slot (16 nodes x 8 channels).
__global__ __launch_bounds__(256) void scatter_k(const float* __restrict__ pos,
                                                 const float* __restrict__ pw,
                                                 const float* __restrict__ cell,
                                                 float* __restrict__ rho) {
    int t = blockIdx.x * blockDim.x + threadIdx.x;
    int p = t >> 2;
    if (p >= NPTS) return;
    int i = t & 3;
    int ix, iy, iz; float wx[4], wy[4], wz[4];
    setup_particle(pos, cell, p, ix, iy, iz, wx, wy, wz);
    const float4 pw0 = *reinterpret_cast<const float4*>(pw + (size_t)p * NCH);
    const float4 pw1 = *reinterpret_cast<const float4*>(pw + (size_t)p * NCH + 4);
    int xi = (ix + i - 1) & (NX - 1);
    float wxi = wx[i];
    #pragma unroll
    for (int j = 0; j < 4; ++j) {
        int yj = (iy + j - 1) & (NY - 1);
        float wxy = wxi * wy[j];
        int base_xy = (xi * NY + yj) * NZ;
        #pragma unroll
        for (int k = 0; k < 4; ++k) {
            int zk = (iz + k - 1) & (NZ - 1);
            float w3 = wxy * wz[k];
            float* node = rho + (size_t)(base_xy + zk) * NCH;
            atomicAdd(node + 0, w3 * pw0.x);
            atomicAdd(node + 1, w3 * pw0.y);
            atomicAdd(node + 2, w3 * pw0.z);
            atomicAdd(node + 3, w3 * pw0.w);
            atomicAdd(node + 4, w3 * pw1.x);
            atomicAdd(node + 5, w3 * pw1.y);
            atomicAdd(node + 6, w3 * pw1.z);
            atomicAdd(node + 7, w3 * pw1.w);
        }
    }
}

// 4 threads per particle; shfl-reduce the 8 channel sums across the 4 lanes.
__global__ __launch_bounds__(256) void gather_k(const float* __restrict__ pos,
                                                const float* __restrict__ cell,
                                                const float* __restrict__ rho,
                                                float* __restrict__ out) {
    int t = blockIdx.x * blockDim.x + threadIdx.x;
    int p = t >> 2;
    if (p >= NPTS) return;
    int i = t & 3;
    int ix, iy, iz; float wx[4], wy[4], wz[4];
    setup_particle(pos, cell, p, ix, iy, iz, wx, wy, wz);
    float acc[8] = {0, 0, 0, 0, 0, 0, 0, 0};
    int xi = (ix + i - 1) & (NX - 1);
    float wxi = wx[i];
    #pragma unroll
    for (int j = 0; j < 4; ++j) {
        int yj = (iy + j - 1) & (NY - 1);
        float wxy = wxi * wy[j];
        int base_xy = (xi * NY + yj) * NZ;
        #pragma unroll
        for (int k = 0; k < 4; ++k) {
            int zk = (iz + k - 1) & (NZ - 1);
            float w3 = wxy * wz[k];
            const float4* node =
                reinterpret_cast<const float4*>(rho + (size_t)(base_xy + zk) * NCH);
            float4 v0 = node[0];
            float4 v1 = node[1];
            acc[0] += w3 * v0.x; acc[1] += w3 * v0.y;
            acc[2] += w3 * v0.z; acc[3] += w3 * v0.w;
            acc[4] += w3 * v1.x; acc[5] += w3 * v1.y;
            acc[6] += w3 * v1.z; acc[7] += w3 * v1.w;
        }
    }
    // reduce over the 4 lanes of this particle group (lanes p*4..p*4+3 are contiguous)
    #pragma unroll
    for (int m = 1; m <= 2; m <<= 1) {
        #pragma unroll
        for (int c = 0; c < 8; ++c) acc[c] += __shfl_xor(acc[c], m, 64);
    }
    if (i == 0) {
        float4* o = reinterpret_cast<float4*>(out + (size_t)p * NCH);
        o[0] = make_float4(acc[0], acc[1], acc[2], acc[3]);
        o[1] = make_float4(acc[4], acc[5], acc[6], acc[7]);
    }
}

extern "C" void kernel_launch(void* const* d_in, const int* in_sizes, int n_in,
                              void* d_out, int out_size, void* d_ws, size_t ws_size,
                              hipStream_t stream) {
    const float* pos  = (const float*)d_in[0];
    const float* pw   = (const float*)d_in[1];
    const float* cell = (const float*)d_in[2];
    float* rho = (float*)d_ws;
    float* out = (float*)d_out;

    size_t mesh_bytes = (size_t)MESH * NCH * sizeof(float);
    hipMemsetAsync(rho, 0, mesh_bytes, stream);

    int threads = NPTS * 4;
    int blocks = (threads + 255) / 256;
    scatter_k<<<blocks, 256, 0, stream>>>(pos, pw, cell, rho);
    gather_k<<<blocks, 256, 0, stream>>>(pos, cell, rho, out);
}

// Round 2
// 558.023 us; speedup vs baseline: 4.8566x; 4.8566x over previous
//
#include <hip/hip_runtime.h>

static constexpr int NX = 128, NY = 128, NZ = 128;
static constexpr int NPTS = 100000;
static constexpr int NCH = 8;
static constexpr int MESH = NX * NY * NZ;   // 2,097,152 nodes
static constexpr int TS = 8;                // tile size (cells/axis)
static constexpr int NT = 16;               // tiles per axis
static constexpr int NTILES = NT * NT * NT; // 4096
static constexpr int RS = TS + 3;           // region nodes/axis = 11
static constexpr int RNODES = RS * RS * RS; // 1331

// P3M order-4 per-axis weights, x in [-1/2, 1/2]
__device__ __forceinline__ void axis_weights(float x, float w[4]) {
    float x2 = x * x, x3 = x2 * x;
    const float c = 1.0f / 48.0f;
    w[0] = c * (1.0f  - 6.0f  * x + 12.0f * x2 - 8.0f  * x3);
    w[1] = c * (23.0f - 30.0f * x - 12.0f * x2 + 24.0f * x3);
    w[2] = c * (23.0f + 30.0f * x - 12.0f * x2 - 24.0f * x3);
    w[3] = c * (1.0f  + 6.0f  * x + 12.0f * x2 + 8.0f  * x3);
}

// Wrapped floor cell index (in [0,128)) + per-axis weights for particle p.
__device__ __forceinline__ void setup_particle(const float* __restrict__ pos,
                                               const float* __restrict__ cell,
                                               int p,
                                               int& ix, int& iy, int& iz,
                                               float wx[4], float wy[4], float wz[4]) {
    float a = cell[0], b = cell[1], c = cell[2];
    float d = cell[3], e = cell[4], f = cell[5];
    float g = cell[6], h = cell[7], i9 = cell[8];
    float c00 = e * i9 - f * h, c01 = f * g - d * i9, c02 = d * h - e * g;
    float c10 = c * h - b * i9, c11 = a * i9 - c * g, c12 = b * g - a * h;
    float c20 = b * f - c * e,  c21 = c * d - a * f,  c22 = a * e - b * d;
    float det = a * c00 + b * c01 + c * c02;
    float s = 128.0f / det;
    float p0 = pos[p * 3 + 0], p1 = pos[p * 3 + 1], p2 = pos[p * 3 + 2];
    float rx = s * (p0 * c00 + p1 * c01 + p2 * c02);
    float ry = s * (p0 * c10 + p1 * c11 + p2 * c12);
    float rz = s * (p0 * c20 + p1 * c21 + p2 * c22);
    float fx = floorf(rx), fy = floorf(ry), fz = floorf(rz);
    ix = ((int)fx) & (NX - 1);
    iy = ((int)fy) & (NY - 1);
    iz = ((int)fz) & (NZ - 1);
    axis_weights(rx - fx - 0.5f, wx);
    axis_weights(ry - fy - 0.5f, wy);
    axis_weights(rz - fz - 0.5f, wz);
}

__device__ __forceinline__ int tile_of(int ix, int iy, int iz) {
    return (((ix >> 3) * NT) + (iy >> 3)) * NT + (iz >> 3);
}

__global__ __launch_bounds__(256) void hist_k(const float* __restrict__ pos,
                                              const float* __restrict__ cell,
                                              int* __restrict__ counts) {
    int p = blockIdx.x * 256 + threadIdx.x;
    if (p >= NPTS) return;
    int ix, iy, iz; float wx[4], wy[4], wz[4];
    setup_particle(pos, cell, p, ix, iy, iz, wx, wy, wz);
    atomicAdd(counts + tile_of(ix, iy, iz), 1);
}

// exclusive prefix sum over 4096 counts -> offsets[0..4096]
__global__ __launch_bounds__(256) void scan_k(const int* __restrict__ counts,
                                              int* __restrict__ offsets) {
    __shared__ int sc[256];
    int tid = threadIdx.x;
    int c[16];
    int s = 0;
    #pragma unroll
    for (int j = 0; j < 16; ++j) { c[j] = counts[tid * 16 + j]; s += c[j]; }
    sc[tid] = s;
    __syncthreads();
    for (int d = 1; d < 256; d <<= 1) {
        int v = (tid >= d) ? sc[tid - d] : 0;
        __syncthreads();
        sc[tid] += v;
        __syncthreads();
    }
    int run = sc[tid] - s;  // exclusive base for this thread's 16 tiles
    #pragma unroll
    for (int j = 0; j < 16; ++j) { offsets[tid * 16 + j] = run; run += c[j]; }
    if (tid == 255) offsets[NTILES] = run;
}

__global__ __launch_bounds__(256) void reorder_k(const float* __restrict__ pos,
                                                 const float* __restrict__ cell,
                                                 const int* __restrict__ offsets,
                                                 int* __restrict__ cursor,
                                                 int* __restrict__ sorted) {
    int p = blockIdx.x * 256 + threadIdx.x;
    if (p >= NPTS) return;
    int ix, iy, iz; float wx[4], wy[4], wz[4];
    setup_particle(pos, cell, p, ix, iy, iz, wx, wy, wz);
    int t = tile_of(ix, iy, iz);
    int slot = atomicAdd(cursor + t, 1);
    sorted[offsets[t] + slot] = p;
}

// One block per tile of the given color. LDS-accumulate the tile+halo region,
// then non-atomic RMW flush to global (same-color regions are disjoint).
__global__ __launch_bounds__(256) void scatter_tile_k(const float* __restrict__ pos,
                                                      const float* __restrict__ pw,
                                                      const float* __restrict__ cell,
                                                      const int* __restrict__ sorted,
                                                      const int* __restrict__ offsets,
                                                      float* __restrict__ rho,
                                                      int color) {
    __shared__ __align__(16) float acc[RNODES * NCH];  // 42,592 B
    int b = blockIdx.x;
    int cx = color & 1, cy = (color >> 1) & 1, cz = (color >> 2) & 1;
    int tx = (((b >> 6) & 7) << 1) | cx;
    int ty = (((b >> 3) & 7) << 1) | cy;
    int tz = ((b & 7) << 1) | cz;
    int tile = (tx * NT + ty) * NT + tz;
    int begin = offsets[tile], end = offsets[tile + 1];

    for (int u = threadIdx.x; u < RNODES * NCH; u += 256) acc[u] = 0.0f;
    __syncthreads();

    int nu = (end - begin) * 16;  // (particle, i, j) work units
    for (int u = threadIdx.x; u < nu; u += 256) {
        int pi = u >> 4, slot = u & 15, i = slot >> 2, j = slot & 3;
        int p = sorted[begin + pi];
        int ix, iy, iz; float wx[4], wy[4], wz[4];
        setup_particle(pos, cell, p, ix, iy, iz, wx, wy, wz);
        const float4 pw0 = *reinterpret_cast<const float4*>(pw + (size_t)p * NCH);
        const float4 pw1 = *reinterpret_cast<const float4*>(pw + (size_t)p * NCH + 4);
        // local coords relative to region origin (tx*TS - 1)
        int lx = ix - tx * TS + i;   // [0,10]
        int ly = iy - ty * TS + j;   // [0,10]
        int lz0 = iz - tz * TS;      // node z = lz0 + k, [0,10]
        float wij = wx[i] * wy[j];
        float* abase = acc + ((lx * RS + ly) * RS + lz0) * NCH;
        #pragma unroll
        for (int k = 0; k < 4; ++k) {
            float w3 = wij * wz[k];
            float* an = abase + k * NCH;
            atomicAdd(an + 0, w3 * pw0.x);
            atomicAdd(an + 1, w3 * pw0.y);
            atomicAdd(an + 2, w3 * pw0.z);
            atomicAdd(an + 3, w3 * pw0.w);
            atomicAdd(an + 4, w3 * pw1.x);
            atomicAdd(an + 5, w3 * pw1.y);
            atomicAdd(an + 6, w3 * pw1.z);
            atomicAdd(an + 7, w3 * pw1.w);
        }
    }
    __syncthreads();

    // flush region to global (non-atomic RMW; disjoint within this dispatch)
    int ox = tx * TS - 1, oy = ty * TS - 1, oz = tz * TS - 1;
    for (int u = threadIdx.x; u < RNODES * 2; u += 256) {
        int node = u >> 1, half = u & 1;
        int lx = node / (RS * RS);
        int rem = node - lx * RS * RS;
        int ly = rem / RS;
        int lz = rem - ly * RS;
        int gx = (ox + lx) & (NX - 1);
        int gy = (oy + ly) & (NY - 1);
        int gz = (oz + lz) & (NZ - 1);
        size_t gi = (size_t)(((gx * NY) + gy) * NZ + gz) * NCH + half * 4;
        float4* g = reinterpret_cast<float4*>(rho + gi);
        float4 v = *g;
        const float4 av = *reinterpret_cast<const float4*>(acc + node * NCH + half * 4);
        v.x += av.x; v.y += av.y; v.z += av.z; v.w += av.w;
        *g = v;
    }
}

// 4 threads per particle; shfl-reduce the 8 channel sums across the 4 lanes.
__global__ __launch_bounds__(256) void gather_k(const float* __restrict__ pos,
                                                const float* __restrict__ cell,
                                                const float* __restrict__ rho,
                                                float* __restrict__ out) {
    int t = blockIdx.x * blockDim.x + threadIdx.x;
    int p = t >> 2;
    if (p >= NPTS) return;
    int i = t & 3;
    int ix, iy, iz; float wx[4], wy[4], wz[4];
    setup_particle(pos, cell, p, ix, iy, iz, wx, wy, wz);
    float acc[8] = {0, 0, 0, 0, 0, 0, 0, 0};
    int xi = (ix + i - 1) & (NX - 1);
    float wxi = wx[i];
    #pragma unroll
    for (int j = 0; j < 4; ++j) {
        int yj = (iy + j - 1) & (NY - 1);
        float wxy = wxi * wy[j];
        int base_xy = (xi * NY + yj) * NZ;
        #pragma unroll
        for (int k = 0; k < 4; ++k) {
            int zk = (iz + k - 1) & (NZ - 1);
            float w3 = wxy * wz[k];
            const float4* node =
                reinterpret_cast<const float4*>(rho + (size_t)(base_xy + zk) * NCH);
            float4 v0 = node[0];
            float4 v1 = node[1];
            acc[0] += w3 * v0.x; acc[1] += w3 * v0.y;
            acc[2] += w3 * v0.z; acc[3] += w3 * v0.w;
            acc[4] += w3 * v1.x; acc[5] += w3 * v1.y;
            acc[6] += w3 * v1.z; acc[7] += w3 * v1.w;
        }
    }
    #pragma unroll
    for (int m = 1; m <= 2; m <<= 1) {
        #pragma unroll
        for (int c = 0; c < 8; ++c) acc[c] += __shfl_xor(acc[c], m, 64);
    }
    if (i == 0) {
        float4* o = reinterpret_cast<float4*>(out + (size_t)p * NCH);
        o[0] = make_float4(acc[0], acc[1], acc[2], acc[3]);
        o[1] = make_float4(acc[4], acc[5], acc[6], acc[7]);
    }
}

extern "C" void kernel_launch(void* const* d_in, const int* in_sizes, int n_in,
                              void* d_out, int out_size, void* d_ws, size_t ws_size,
                              hipStream_t stream) {
    const float* pos  = (const float*)d_in[0];
    const float* pw   = (const float*)d_in[1];
    const float* cell = (const float*)d_in[2];
    float* rho = (float*)d_ws;           // 64 MiB mesh
    float* out = (float*)d_out;

    // Small scratch lives at the start of d_out (449 KB of 3.2 MB). Legal:
    // gather_k runs last and overwrites every element of d_out.
    int* counts  = (int*)d_out;
    int* cursor  = counts + NTILES;
    int* offsets = cursor + NTILES;      // NTILES+1 entries
    int* sorted  = offsets + NTILES + 1; // NPTS entries

    hipMemsetAsync(rho, 0, (size_t)MESH * NCH * sizeof(float), stream);
    hipMemsetAsync(counts, 0, 2 * NTILES * sizeof(int), stream);

    int pblocks = (NPTS + 255) / 256;
    hist_k<<<pblocks, 256, 0, stream>>>(pos, cell, counts);
    scan_k<<<1, 256, 0, stream>>>(counts, offsets);
    reorder_k<<<pblocks, 256, 0, stream>>>(pos, cell, offsets, cursor, sorted);

    for (int c = 0; c < 8; ++c) {
        scatter_tile_k<<<NTILES / 8, 256, 0, stream>>>(pos, pw, cell, sorted,
                                                       offsets, rho, c);
    }

    int gblocks = (NPTS * 4 + 255) / 256;
    gather_k<<<gblocks, 256, 0, stream>>>(pos, cell, rho, out);
}

// Round 3
// 209.181 us; speedup vs baseline: 12.9558x; 2.6677x over previous
//
#include <hip/hip_runtime.h>

static constexpr int NXC   = 128;              // cells per axis
static constexpr int NPTS  = 100000;
static constexpr int NCH   = 8;
static constexpr int TS    = 8;                // tile cells/axis
static constexpr int NT    = 16;               // tiles/axis
static constexpr int NTILES = NT * NT * NT;    // 4096
static constexpr int REC   = 20;               // floats per particle record (5 float4)
static constexpr int CMAX  = 512;              // max candidates per block (E≈131)
static constexpr int PMAX  = 2048;             // max pairs per block (E≈400)
static constexpr int OMAX  = 128;              // max owned per block (E≈24)

// P3M order-4 per-axis weights, x in [-1/2, 1/2]
__device__ __forceinline__ void axis_weights(float x, float w[4]) {
    float x2 = x * x, x3 = x2 * x;
    const float c = 1.0f / 48.0f;
    w[0] = c * (1.0f  - 6.0f  * x + 12.0f * x2 - 8.0f  * x3);
    w[1] = c * (23.0f - 30.0f * x - 12.0f * x2 + 24.0f * x3);
    w[2] = c * (23.0f + 30.0f * x - 12.0f * x2 - 24.0f * x3);
    w[3] = c * (1.0f  + 6.0f  * x + 12.0f * x2 + 8.0f  * x3);
}

// Mesh-scaled fractional coords (identical FP sequence in every kernel).
__device__ __forceinline__ void mesh_coords(const float* __restrict__ pos,
                                            const float* __restrict__ cell,
                                            int p, float& rx, float& ry, float& rz) {
    float a = cell[0], b = cell[1], c = cell[2];
    float d = cell[3], e = cell[4], f = cell[5];
    float g = cell[6], h = cell[7], i9 = cell[8];
    float c00 = e * i9 - f * h, c01 = f * g - d * i9, c02 = d * h - e * g;
    float c10 = c * h - b * i9, c11 = a * i9 - c * g, c12 = b * g - a * h;
    float c20 = b * f - c * e,  c21 = c * d - a * f,  c22 = a * e - b * d;
    float det = a * c00 + b * c01 + c * c02;
    float s = 128.0f / det;
    float p0 = pos[p * 3 + 0], p1 = pos[p * 3 + 1], p2 = pos[p * 3 + 2];
    rx = s * (p0 * c00 + p1 * c01 + p2 * c02);
    ry = s * (p0 * c10 + p1 * c11 + p2 * c12);
    rz = s * (p0 * c20 + p1 * c21 + p2 * c22);
}

__device__ __forceinline__ int wrap_cell(float r) {
    return ((int)floorf(r)) & (NXC - 1);
}

__global__ __launch_bounds__(256) void hist_k(const float* __restrict__ pos,
                                              const float* __restrict__ cell,
                                              int* __restrict__ counts) {
    int p = blockIdx.x * 256 + threadIdx.x;
    if (p >= NPTS) return;
    float rx, ry, rz;
    mesh_coords(pos, cell, p, rx, ry, rz);
    int ix = wrap_cell(rx), iy = wrap_cell(ry), iz = wrap_cell(rz);
    int tile = ((ix >> 3) * NT + (iy >> 3)) * NT + (iz >> 3);
    atomicAdd(counts + tile, 1);
}

// exclusive prefix sum over 4096 counts -> offsets[0..4096]
__global__ __launch_bounds__(256) void scan_k(const int* __restrict__ counts,
                                              int* __restrict__ offsets) {
    __shared__ int sc[256];
    int tid = threadIdx.x;
    int c[16];
    int s = 0;
    #pragma unroll
    for (int j = 0; j < 16; ++j) { c[j] = counts[tid * 16 + j]; s += c[j]; }
    sc[tid] = s;
    __syncthreads();
    for (int d = 1; d < 256; d <<= 1) {
        int v = (tid >= d) ? sc[tid - d] : 0;
        __syncthreads();
        sc[tid] += v;
        __syncthreads();
    }
    int run = sc[tid] - s;
    #pragma unroll
    for (int j = 0; j < 16; ++j) { offsets[tid * 16 + j] = run; run += c[j]; }
    if (tid == 255) offsets[NTILES] = run;
}

// Bin particles by tile; emit packed cell, original pid, and a 5-float4 record:
// [wx0..3][wy0..3][wz0..3][ch0..3][ch4..7]
__global__ __launch_bounds__(256) void reorder_k(const float* __restrict__ pos,
                                                 const float* __restrict__ pw,
                                                 const float* __restrict__ cell,
                                                 const int* __restrict__ offsets,
                                                 int* __restrict__ cursor,
                                                 int* __restrict__ scell,
                                                 int* __restrict__ spid,
                                                 float* __restrict__ srec) {
    int p = blockIdx.x * 256 + threadIdx.x;
    if (p >= NPTS) return;
    float rx, ry, rz;
    mesh_coords(pos, cell, p, rx, ry, rz);
    float fx = floorf(rx), fy = floorf(ry), fz = floorf(rz);
    int ix = ((int)fx) & (NXC - 1), iy = ((int)fy) & (NXC - 1), iz = ((int)fz) & (NXC - 1);
    int tile = ((ix >> 3) * NT + (iy >> 3)) * NT + (iz >> 3);
    int slot = atomicAdd(cursor + tile, 1);
    int idx = offsets[tile] + slot;
    scell[idx] = ix | (iy << 8) | (iz << 16);
    spid[idx] = p;
    float wx[4], wy[4], wz[4];
    axis_weights(rx - fx - 0.5f, wx);
    axis_weights(ry - fy - 0.5f, wy);
    axis_weights(rz - fz - 0.5f, wz);
    float4* r = reinterpret_cast<float4*>(srec) + (size_t)idx * 5;
    r[0] = make_float4(wx[0], wx[1], wx[2], wx[3]);
    r[1] = make_float4(wy[0], wy[1], wy[2], wy[3]);
    r[2] = make_float4(wz[0], wz[1], wz[2], wz[3]);
    const float4* pw4 = reinterpret_cast<const float4*>(pw + (size_t)p * NCH);
    r[3] = pw4[0];
    r[4] = pw4[1];
}

// Sx(d) = sum_m wp[m] * wq[m-d], zero outside [0,3]; d in [-3,3].
__device__ __forceinline__ float corr4(float4 wp, float4 wq, int d) {
    float s0 = d == 0 ? wq.x : d == -1 ? wq.y : d == -2 ? wq.z : d == -3 ? wq.w : 0.0f;
    float s1 = d == 1 ? wq.x : d ==  0 ? wq.y : d == -1 ? wq.z : d == -2 ? wq.w : 0.0f;
    float s2 = d == 2 ? wq.x : d ==  1 ? wq.y : d ==  0 ? wq.z : d == -1 ? wq.w : 0.0f;
    float s3 = d == 3 ? wq.x : d ==  2 ? wq.y : d ==  1 ? wq.z : d ==  0 ? wq.w : 0.0f;
    return wp.x * s0 + wp.y * s1 + wp.z * s2 + wp.w * s3;
}

// One block per tile: out[p] = sum_q (Sx*Sy*Sz) * ch_q over neighbor pairs.
__global__ __launch_bounds__(256) void pair_k(const int* __restrict__ offsets,
                                              const int* __restrict__ scell,
                                              const int* __restrict__ spid,
                                              const float* __restrict__ srec,
                                              float* __restrict__ out) {
    __shared__ int cidx[CMAX];
    __shared__ int ccell[CMAX];
    __shared__ int plist[PMAX];
    __shared__ int ocellS[OMAX];
    __shared__ __align__(16) float orec[OMAX * 12];  // owned wx/wy/wz
    __shared__ float acc[OMAX * 9];                  // stride 9: bank-spread
    __shared__ int ncand, npair;

    int b = blockIdx.x;
    int tx = b >> 8, ty = (b >> 4) & 15, tz = b & 15;
    int tid = threadIdx.x;
    int begin = offsets[b], end = offsets[b + 1];
    int nown = end - begin;
    if (nown == 0) return;  // uniform across block; no syncthreads crossed yet
    if (tid == 0) { ncand = 0; npair = 0; }
    __syncthreads();

    for (int i = tid; i < nown * 9; i += 256) acc[i] = 0.0f;
    for (int i = tid; i < nown; i += 256) ocellS[i] = scell[begin + i];
    {   // stage owned weight records (wx,wy,wz = 3 float4 each)
        const float4* recs = reinterpret_cast<const float4*>(srec);
        float4* od = reinterpret_cast<float4*>(orec);
        for (int i = tid; i < nown * 3; i += 256) {
            int p = i / 3, k = i - p * 3;
            od[p * 3 + k] = recs[(size_t)(begin + p) * 5 + k];
        }
    }
    // candidate filter: particles of 27 neighbor tiles within the 14^3-cell halo
    int base_x = tx * TS - 3, base_y = ty * TS - 3, base_z = tz * TS - 3;
    for (int n = 0; n < 27; ++n) {
        int ox = n / 9 - 1, oy = (n / 3) % 3 - 1, oz = n % 3 - 1;
        int nt = ((((tx + ox) & 15) * NT + ((ty + oy) & 15)) * NT) + ((tz + oz) & 15);
        int b0 = offsets[nt], b1 = offsets[nt + 1];
        for (int i = b0 + tid; i < b1; i += 256) {
            int c = scell[i];
            bool pass = (((c & 255)         - base_x) & 127) < 14
                     && ((((c >> 8) & 255)  - base_y) & 127) < 14
                     && ((((c >> 16) & 255) - base_z) & 127) < 14;
            if (pass) {
                int k = atomicAdd(&ncand, 1);
                if (k < CMAX) { cidx[k] = i; ccell[k] = c; }
            }
        }
    }
    __syncthreads();
    int nc = min(ncand, CMAX);

    // phase A: enumerate interacting pairs (|d|<=3 per axis, periodic)
    for (int p = 0; p < nown; ++p) {
        int pc = ocellS[p];
        int px = pc & 255, py = (pc >> 8) & 255, pz = (pc >> 16) & 255;
        for (int j = tid; j < nc; j += 256) {
            int qc = ccell[j];
            int dx = (((qc & 255) - px) & 127);         if (dx > 63) dx -= 128;
            int dy = ((((qc >> 8) & 255) - py) & 127);  if (dy > 63) dy -= 128;
            int dz = ((((qc >> 16) & 255) - pz) & 127); if (dz > 63) dz -= 128;
            if ((unsigned)(dx + 3) <= 6u && (unsigned)(dy + 3) <= 6u &&
                (unsigned)(dz + 3) <= 6u) {
                int k = atomicAdd(&npair, 1);
                if (k < PMAX) plist[k] = (p << 9) | j;
            }
        }
    }
    __syncthreads();
    int np = min(npair, PMAX);

    // phase B: dense pair evaluation
    const float4* recs = reinterpret_cast<const float4*>(srec);
    const float4* ow = reinterpret_cast<const float4*>(orec);
    for (int u = tid; u < np; u += 256) {
        int pk = plist[u];
        int p = pk >> 9, j = pk & 511;
        int qc = ccell[j], pc = ocellS[p];
        int dx = (((qc & 255) - (pc & 255)) & 127);                 if (dx > 63) dx -= 128;
        int dy = ((((qc >> 8) & 255) - ((pc >> 8) & 255)) & 127);   if (dy > 63) dy -= 128;
        int dz = ((((qc >> 16) & 255) - ((pc >> 16) & 255)) & 127); if (dz > 63) dz -= 128;
        float4 pxw = ow[p * 3 + 0], pyw = ow[p * 3 + 1], pzw = ow[p * 3 + 2];
        const float4* rq = recs + (size_t)cidx[j] * 5;
        float4 qxw = rq[0], qyw = rq[1], qzw = rq[2];
        float4 qc0 = rq[3], qc1 = rq[4];
        float S = corr4(pxw, qxw, dx) * corr4(pyw, qyw, dy) * corr4(pzw, qzw, dz);
        float* a = acc + p * 9;
        atomicAdd(a + 0, S * qc0.x);
        atomicAdd(a + 1, S * qc0.y);
        atomicAdd(a + 2, S * qc0.z);
        atomicAdd(a + 3, S * qc0.w);
        atomicAdd(a + 4, S * qc1.x);
        atomicAdd(a + 5, S * qc1.y);
        atomicAdd(a + 6, S * qc1.z);
        atomicAdd(a + 7, S * qc1.w);
    }
    __syncthreads();

    for (int i = tid; i < nown * NCH; i += 256) {
        int p = i >> 3, c = i & 7;
        out[(size_t)spid[begin + p] * NCH + c] = acc[p * 9 + c];
    }
}

extern "C" void kernel_launch(void* const* d_in, const int* in_sizes, int n_in,
                              void* d_out, int out_size, void* d_ws, size_t ws_size,
                              hipStream_t stream) {
    const float* pos  = (const float*)d_in[0];
    const float* pw   = (const float*)d_in[1];
    const float* cell = (const float*)d_in[2];
    float* out = (float*)d_out;

    float* srec   = (float*)d_ws;                 // NPTS*20 floats (16B aligned)
    int*   scell  = (int*)(srec + (size_t)NPTS * REC);
    int*   spid   = scell + NPTS;
    int*   counts = spid + NPTS;
    int*   cursor = counts + NTILES;
    int*   offsets = cursor + NTILES;             // NTILES+1

    hipMemsetAsync(counts, 0, 2 * NTILES * sizeof(int), stream);

    int pblocks = (NPTS + 255) / 256;
    hist_k<<<pblocks, 256, 0, stream>>>(pos, cell, counts);
    scan_k<<<1, 256, 0, stream>>>(counts, offsets);
    reorder_k<<<pblocks, 256, 0, stream>>>(pos, pw, cell, offsets, cursor,
                                           scell, spid, srec);
    pair_k<<<NTILES, 256, 0, stream>>>(offsets, scell, spid, srec, out);
}

// Round 4
// 140.151 us; speedup vs baseline: 19.3370x; 1.4925x over previous
//
#include <hip/hip_runtime.h>

static constexpr int NXC   = 128;              // cells per axis
static constexpr int NPTS  = 100000;
static constexpr int NCH   = 8;
static constexpr int TS    = 8;                // tile cells/axis
static constexpr int NT    = 16;               // tiles/axis
static constexpr int NTILES = NT * NT * NT;    // 4096
static constexpr int REC   = 20;               // floats per particle record (5 float4)
static constexpr int CMAX  = 320;              // max candidates per block (E≈131, +16σ)

// P3M order-4 per-axis weights, x in [-1/2, 1/2]
__device__ __forceinline__ void axis_weights(float x, float w[4]) {
    float x2 = x * x, x3 = x2 * x;
    const float c = 1.0f / 48.0f;
    w[0] = c * (1.0f  - 6.0f  * x + 12.0f * x2 - 8.0f  * x3);
    w[1] = c * (23.0f - 30.0f * x - 12.0f * x2 + 24.0f * x3);
    w[2] = c * (23.0f + 30.0f * x - 12.0f * x2 - 24.0f * x3);
    w[3] = c * (1.0f  + 6.0f  * x + 12.0f * x2 + 8.0f  * x3);
}

// Mesh-scaled fractional coords (identical FP sequence in every kernel).
__device__ __forceinline__ void mesh_coords(const float* __restrict__ pos,
                                            const float* __restrict__ cell,
                                            int p, float& rx, float& ry, float& rz) {
    float a = cell[0], b = cell[1], c = cell[2];
    float d = cell[3], e = cell[4], f = cell[5];
    float g = cell[6], h = cell[7], i9 = cell[8];
    float c00 = e * i9 - f * h, c01 = f * g - d * i9, c02 = d * h - e * g;
    float c10 = c * h - b * i9, c11 = a * i9 - c * g, c12 = b * g - a * h;
    float c20 = b * f - c * e,  c21 = c * d - a * f,  c22 = a * e - b * d;
    float det = a * c00 + b * c01 + c * c02;
    float s = 128.0f / det;
    float p0 = pos[p * 3 + 0], p1 = pos[p * 3 + 1], p2 = pos[p * 3 + 2];
    rx = s * (p0 * c00 + p1 * c01 + p2 * c02);
    ry = s * (p0 * c10 + p1 * c11 + p2 * c12);
    rz = s * (p0 * c20 + p1 * c21 + p2 * c22);
}

__global__ __launch_bounds__(256) void hist_k(const float* __restrict__ pos,
                                              const float* __restrict__ cell,
                                              int* __restrict__ counts) {
    int p = blockIdx.x * 256 + threadIdx.x;
    if (p >= NPTS) return;
    float rx, ry, rz;
    mesh_coords(pos, cell, p, rx, ry, rz);
    int ix = ((int)floorf(rx)) & (NXC - 1);
    int iy = ((int)floorf(ry)) & (NXC - 1);
    int iz = ((int)floorf(rz)) & (NXC - 1);
    int tile = ((ix >> 3) * NT + (iy >> 3)) * NT + (iz >> 3);
    atomicAdd(counts + tile, 1);
}

// exclusive prefix sum over 4096 counts -> offsets[0..4096]
__global__ __launch_bounds__(256) void scan_k(const int* __restrict__ counts,
                                              int* __restrict__ offsets) {
    __shared__ int sc[256];
    int tid = threadIdx.x;
    int c[16];
    int s = 0;
    #pragma unroll
    for (int j = 0; j < 16; ++j) { c[j] = counts[tid * 16 + j]; s += c[j]; }
    sc[tid] = s;
    __syncthreads();
    for (int d = 1; d < 256; d <<= 1) {
        int v = (tid >= d) ? sc[tid - d] : 0;
        __syncthreads();
        sc[tid] += v;
        __syncthreads();
    }
    int run = sc[tid] - s;
    #pragma unroll
    for (int j = 0; j < 16; ++j) { offsets[tid * 16 + j] = run; run += c[j]; }
    if (tid == 255) offsets[NTILES] = run;
}

// Bin particles by tile; emit packed cell, original pid, and a 5-float4 record:
// [wx0..3][wy0..3][wz0..3][ch0..3][ch4..7]
__global__ __launch_bounds__(256) void reorder_k(const float* __restrict__ pos,
                                                 const float* __restrict__ pw,
                                                 const float* __restrict__ cell,
                                                 const int* __restrict__ offsets,
                                                 int* __restrict__ cursor,
                                                 int* __restrict__ scell,
                                                 int* __restrict__ spid,
                                                 float* __restrict__ srec) {
    int p = blockIdx.x * 256 + threadIdx.x;
    if (p >= NPTS) return;
    float rx, ry, rz;
    mesh_coords(pos, cell, p, rx, ry, rz);
    float fx = floorf(rx), fy = floorf(ry), fz = floorf(rz);
    int ix = ((int)fx) & (NXC - 1), iy = ((int)fy) & (NXC - 1), iz = ((int)fz) & (NXC - 1);
    int tile = ((ix >> 3) * NT + (iy >> 3)) * NT + (iz >> 3);
    int slot = atomicAdd(cursor + tile, 1);
    int idx = offsets[tile] + slot;
    scell[idx] = ix | (iy << 8) | (iz << 16);
    spid[idx] = p;
    float wx[4], wy[4], wz[4];
    axis_weights(rx - fx - 0.5f, wx);
    axis_weights(ry - fy - 0.5f, wy);
    axis_weights(rz - fz - 0.5f, wz);
    float4* r = reinterpret_cast<float4*>(srec) + (size_t)idx * 5;
    r[0] = make_float4(wx[0], wx[1], wx[2], wx[3]);
    r[1] = make_float4(wy[0], wy[1], wy[2], wy[3]);
    r[2] = make_float4(wz[0], wz[1], wz[2], wz[3]);
    const float4* pw4 = reinterpret_cast<const float4*>(pw + (size_t)p * NCH);
    r[3] = pw4[0];
    r[4] = pw4[1];
}

// Sx(d) = sum_m wp[m] * wq[m-d], zero outside [0,3]; d in [-3,3].
__device__ __forceinline__ float corr4(float4 wp, float4 wq, int d) {
    float s0 = d == 0 ? wq.x : d == -1 ? wq.y : d == -2 ? wq.z : d == -3 ? wq.w : 0.0f;
    float s1 = d == 1 ? wq.x : d ==  0 ? wq.y : d == -1 ? wq.z : d == -2 ? wq.w : 0.0f;
    float s2 = d == 2 ? wq.x : d ==  1 ? wq.y : d ==  0 ? wq.z : d == -1 ? wq.w : 0.0f;
    float s3 = d == 3 ? wq.x : d ==  2 ? wq.y : d ==  0 + 2 ? wq.z : d == 0 ? wq.w : 0.0f;
    // NOTE: s3 rewritten explicitly below to avoid typo risk
    s3 = d == 3 ? wq.x : d == 2 ? wq.y : d == 1 ? wq.z : d == 0 ? wq.w : 0.0f;
    return wp.x * s0 + wp.y * s1 + wp.z * s2 + wp.w * s3;
}

// One block per tile. Stage filtered candidates (cell + 80B record) into LDS
// with flat parallel loops; then 8 lanes per owned particle gather-accumulate
// in registers and shfl-reduce. Two barriers total, no serial loops.
__global__ __launch_bounds__(256) void pair_k(const int* __restrict__ offsets,
                                              const int* __restrict__ scell,
                                              const int* __restrict__ spid,
                                              const float* __restrict__ srec,
                                              float* __restrict__ out) {
    __shared__ int ccell[CMAX];
    __shared__ __align__(16) float crec[CMAX * REC];  // 25.6 KB
    __shared__ int nb0[27];
    __shared__ int nbase[28];
    __shared__ int ncand;

    int b = blockIdx.x;
    int tx = b >> 8, ty = (b >> 4) & 15, tz = b & 15;
    int tid = threadIdx.x;
    int begin = offsets[b], end = offsets[b + 1];
    int nown = end - begin;
    if (nown == 0) return;  // uniform; no barrier crossed yet

    if (tid < 27) {
        int n = tid;
        int ox = n / 9 - 1, oy = (n / 3) % 3 - 1, oz = n % 3 - 1;
        int nt = ((((tx + ox) & 15) * NT + ((ty + oy) & 15)) * NT) + ((tz + oz) & 15);
        int b0 = offsets[nt];
        nb0[n] = b0;
        nbase[n] = offsets[nt + 1] - b0;  // count; scanned below
    }
    if (tid == 0) ncand = 0;
    __syncthreads();
    if (tid == 0) {
        int run = 0;
        #pragma unroll
        for (int n = 0; n < 27; ++n) { int c = nbase[n]; nbase[n] = run; run += c; }
        nbase[27] = run;
    }
    __syncthreads();
    int tc = nbase[27];

    // stage candidates: flat loop over all neighbor particles, 14^3-halo filter
    int base_x = tx * TS - 3, base_y = ty * TS - 3, base_z = tz * TS - 3;
    const float4* recs = reinterpret_cast<const float4*>(srec);
    for (int u = tid; u < tc; u += 256) {
        int lo = 0, hi = 27;
        while (hi - lo > 1) { int mid = (lo + hi) >> 1; if (nbase[mid] <= u) lo = mid; else hi = mid; }
        int i = nb0[lo] + (u - nbase[lo]);
        int c = scell[i];
        bool pass = (((c & 255)         - base_x) & 127) < 14
                 && ((((c >> 8) & 255)  - base_y) & 127) < 14
                 && ((((c >> 16) & 255) - base_z) & 127) < 14;
        if (pass) {
            int k = atomicAdd(&ncand, 1);
            if (k < CMAX) {
                ccell[k] = c;
                const float4* r = recs + (size_t)i * 5;
                float4* d = reinterpret_cast<float4*>(crec + k * REC);
                d[0] = r[0]; d[1] = r[1]; d[2] = r[2]; d[3] = r[3]; d[4] = r[4];
            }
        }
    }
    __syncthreads();
    int nc = min(ncand, CMAX);

    // gather: 8 lanes per owned particle, register accumulation
    int sub = tid & 7, pg = tid >> 3;  // 32 groups of 8
    for (int p0 = 0; p0 < nown; p0 += 32) {
        int p = p0 + pg;
        bool live = p < nown;
        float acc[8] = {0, 0, 0, 0, 0, 0, 0, 0};
        if (live) {
            int pc = scell[begin + p];
            int px = pc & 255, py = (pc >> 8) & 255, pz = (pc >> 16) & 255;
            const float4* r = recs + (size_t)(begin + p) * 5;
            float4 pxw = r[0], pyw = r[1], pzw = r[2];
            for (int j = sub; j < nc; j += 8) {
                int qc = ccell[j];
                int dx = (((qc & 255) - px) & 127);         if (dx > 63) dx -= 128;
                int dy = ((((qc >> 8) & 255) - py) & 127);  if (dy > 63) dy -= 128;
                int dz = ((((qc >> 16) & 255) - pz) & 127); if (dz > 63) dz -= 128;
                if ((unsigned)(dx + 3) <= 6u && (unsigned)(dy + 3) <= 6u &&
                    (unsigned)(dz + 3) <= 6u) {
                    const float4* q = reinterpret_cast<const float4*>(crec + j * REC);
                    float4 qxw = q[0], qyw = q[1], qzw = q[2];
                    float S = corr4(pxw, qxw, dx) * corr4(pyw, qyw, dy) *
                              corr4(pzw, qzw, dz);
                    float4 ch0 = q[3], ch1 = q[4];
                    acc[0] += S * ch0.x; acc[1] += S * ch0.y;
                    acc[2] += S * ch0.z; acc[3] += S * ch0.w;
                    acc[4] += S * ch1.x; acc[5] += S * ch1.y;
                    acc[6] += S * ch1.z; acc[7] += S * ch1.w;
                }
            }
        }
        // reduce across the 8 lanes of the group (wave-uniform execution here)
        #pragma unroll
        for (int m = 1; m <= 4; m <<= 1) {
            #pragma unroll
            for (int c = 0; c < 8; ++c) acc[c] += __shfl_xor(acc[c], m, 64);
        }
        if (live && sub == 0) {
            int pid = spid[begin + p];
            float4* o = reinterpret_cast<float4*>(out + (size_t)pid * NCH);
            o[0] = make_float4(acc[0], acc[1], acc[2], acc[3]);
            o[1] = make_float4(acc[4], acc[5], acc[6], acc[7]);
        }
    }
}

extern "C" void kernel_launch(void* const* d_in, const int* in_sizes, int n_in,
                              void* d_out, int out_size, void* d_ws, size_t ws_size,
                              hipStream_t stream) {
    const float* pos  = (const float*)d_in[0];
    const float* pw   = (const float*)d_in[1];
    const float* cell = (const float*)d_in[2];
    float* out = (float*)d_out;

    float* srec   = (float*)d_ws;                 // NPTS*20 floats (16B aligned)
    int*   scell  = (int*)(srec + (size_t)NPTS * REC);
    int*   spid   = scell + NPTS;
    int*   counts = spid + NPTS;
    int*   cursor = counts + NTILES;
    int*   offsets = cursor + NTILES;             // NTILES+1

    hipMemsetAsync(counts, 0, 2 * NTILES * sizeof(int), stream);

    int pblocks = (NPTS + 255) / 256;
    hist_k<<<pblocks, 256, 0, stream>>>(pos, cell, counts);
    scan_k<<<1, 256, 0, stream>>>(counts, offsets);
    reorder_k<<<pblocks, 256, 0, stream>>>(pos, pw, cell, offsets, cursor,
                                           scell, spid, srec);
    pair_k<<<NTILES, 256, 0, stream>>>(offsets, scell, spid, srec, out);
}